// Round 1
// baseline (509.442 us; speedup 1.0000x reference)
//
#include <hip/hip_runtime.h>

#define F 64
#define BN_EPS 1e-5f

// ---------------- Kernel 1: edge scatter-add ----------------
// One wave (64 lanes) per edge; lane = feature index.
__global__ __launch_bounds__(256) void scatter_add_kernel(
    const float* __restrict__ x,
    const int* __restrict__ row,
    const int* __restrict__ col,
    float* __restrict__ agg,
    int nEdges)
{
    const int lane = threadIdx.x & 63;
    const int waveId = (blockIdx.x * blockDim.x + threadIdx.x) >> 6;
    const int nWaves = (gridDim.x * blockDim.x) >> 6;
    for (int e = waveId; e < nEdges; e += nWaves) {
        const int r = row[e];
        const int c = col[e];
        if (r != c) {
            atomicAdd(&agg[r * F + lane], x[c * F + lane]);
        }
    }
}

// ---------------- Kernel 2: fused (x+agg) -> Lin1+ReLU -> Lin2+ReLU -> stats ----------------
// One wave per node row; lane = output feature. Weights in LDS.
__global__ __launch_bounds__(256) void mlp_stats_kernel(
    const float* __restrict__ x,
    const float* __restrict__ agg,
    const float* __restrict__ W1,
    const float* __restrict__ b1,
    const float* __restrict__ W2,
    const float* __restrict__ b2,
    float* __restrict__ h_out,      // d_out, holds h2 pre-BN
    float* __restrict__ stats,      // [0..63]=sum, [64..127]=sumsq
    int nNodes)
{
    __shared__ float sW1[F * F];
    __shared__ float sW2[F * F];
    __shared__ float sb1[F];
    __shared__ float sb2[F];

    for (int i = threadIdx.x; i < F * F; i += blockDim.x) {
        sW1[i] = W1[i];
        sW2[i] = W2[i];
    }
    if (threadIdx.x < F) {
        sb1[threadIdx.x] = b1[threadIdx.x];
        sb2[threadIdx.x] = b2[threadIdx.x];
    }
    __syncthreads();

    const int lane = threadIdx.x & 63;
    const int waveInBlock = threadIdx.x >> 6;
    const int waveId = blockIdx.x * (blockDim.x >> 6) + waveInBlock;
    const int nWaves = gridDim.x * (blockDim.x >> 6);

    float ssum = 0.0f;
    float ssq  = 0.0f;

    for (int r = waveId; r < nNodes; r += nWaves) {
        const float v = x[r * F + lane] + agg[r * F + lane];

        // layer 1: h1[lane] = relu(b1[lane] + sum_k v[k] * W1[k][lane])
        float acc = sb1[lane];
        #pragma unroll
        for (int k = 0; k < F; ++k) {
            const float xv = __shfl(v, k, 64);
            acc = fmaf(xv, sW1[k * F + lane], acc);
        }
        acc = fmaxf(acc, 0.0f);

        // layer 2
        float acc2 = sb2[lane];
        #pragma unroll
        for (int k = 0; k < F; ++k) {
            const float hv = __shfl(acc, k, 64);
            acc2 = fmaf(hv, sW2[k * F + lane], acc2);
        }
        acc2 = fmaxf(acc2, 0.0f);

        h_out[r * F + lane] = acc2;
        ssum += acc2;
        ssq = fmaf(acc2, acc2, ssq);
    }

    // block reduction: per-wave partials -> per-block -> global atomics
    __shared__ float red[2][4][F];
    red[0][waveInBlock][lane] = ssum;
    red[1][waveInBlock][lane] = ssq;
    __syncthreads();
    if (threadIdx.x < F) {
        const int f = threadIdx.x;
        const float s = red[0][0][f] + red[0][1][f] + red[0][2][f] + red[0][3][f];
        const float q = red[1][0][f] + red[1][1][f] + red[1][2][f] + red[1][3][f];
        atomicAdd(&stats[f], s);
        atomicAdd(&stats[F + f], q);
    }
}

// ---------------- Kernel 3: BN finalize + normalize in place ----------------
__global__ __launch_bounds__(256) void bn_normalize_kernel(
    float* __restrict__ h,          // d_out, in place
    const float* __restrict__ stats,
    const float* __restrict__ gamma,
    const float* __restrict__ beta,
    int nNodes)
{
    __shared__ float sscale[F];
    __shared__ float sshift[F];
    if (threadIdx.x < F) {
        const int f = threadIdx.x;
        const float invN = 1.0f / (float)nNodes;
        const float mean = stats[f] * invN;
        const float var  = stats[F + f] * invN - mean * mean;
        const float inv  = rsqrtf(var + BN_EPS);
        const float g    = gamma[f];
        sscale[f] = inv * g;
        sshift[f] = beta[f] - mean * inv * g;
    }
    __syncthreads();

    const int total = nNodes * F;
    const int stride = gridDim.x * blockDim.x;
    for (int i = blockIdx.x * blockDim.x + threadIdx.x; i < total; i += stride) {
        const int f = i & 63;
        h[i] = fmaf(h[i], sscale[f], sshift[f]);
    }
}

extern "C" void kernel_launch(void* const* d_in, const int* in_sizes, int n_in,
                              void* d_out, int out_size, void* d_ws, size_t ws_size,
                              hipStream_t stream)
{
    const float* x     = (const float*)d_in[0];
    const int*   eidx  = (const int*)d_in[1];   // [2, E] row-major: row then col
    const float* W1    = (const float*)d_in[2];
    const float* b1    = (const float*)d_in[3];
    const float* W2    = (const float*)d_in[4];
    const float* b2    = (const float*)d_in[5];
    const float* gamma = (const float*)d_in[6];
    const float* beta  = (const float*)d_in[7];

    const int nNodes = in_sizes[0] / F;
    const int nEdges = in_sizes[1] / 2;
    const int* row = eidx;
    const int* col = eidx + nEdges;

    float* agg   = (float*)d_ws;                       // [nNodes * F]
    float* stats = (float*)((char*)d_ws + (size_t)nNodes * F * sizeof(float)); // [128]
    float* hbuf  = (float*)d_out;

    // zero agg + stats (poisoned 0xAA before timing; must re-zero every call)
    hipMemsetAsync(d_ws, 0, (size_t)nNodes * F * sizeof(float) + 128 * sizeof(float), stream);

    // scatter: grid-stride, 4 waves/block
    {
        const int blocks = 8192;
        scatter_add_kernel<<<blocks, 256, 0, stream>>>(x, row, col, agg, nEdges);
    }

    // fused MLP + BN stats
    {
        const int blocks = 2048;
        mlp_stats_kernel<<<blocks, 256, 0, stream>>>(x, agg, W1, b1, W2, b2,
                                                     hbuf, stats, nNodes);
    }

    // BN normalize in place
    {
        const int blocks = 2048;
        bn_normalize_kernel<<<blocks, 256, 0, stream>>>(hbuf, stats, gamma, beta, nNodes);
    }
}

// Round 2
// 490.861 us; speedup vs baseline: 1.0379x; 1.0379x over previous
//
#include <hip/hip_runtime.h>

#define F 64
#define BN_EPS 1e-5f

// ---------------- Kernel 1: degree histogram + per-edge rank ----------------
__global__ __launch_bounds__(256) void hist_kernel(
    const int* __restrict__ row,
    const int* __restrict__ col,
    int* __restrict__ counts,   // [N], pre-zeroed
    int* __restrict__ rank,     // [E]
    int nEdges)
{
    const int stride = gridDim.x * blockDim.x;
    for (int e = blockIdx.x * blockDim.x + threadIdx.x; e < nEdges; e += stride) {
        const int r = row[e];
        const int c = col[e];
        if (r != c) {
            rank[e] = atomicAdd(&counts[r], 1);
        }
    }
}

// ---------------- Kernel 2a: per-block inclusive scan of counts ----------------
__global__ __launch_bounds__(256) void scan1_kernel(
    const int* __restrict__ counts,
    int* __restrict__ starts,       // [N+1], exclusive-within-block written here
    int* __restrict__ blocksums,    // [nblocks]
    int n)
{
    __shared__ int tmp[256];
    const int t = threadIdx.x;
    const int i = blockIdx.x * 256 + t;
    const int v = (i < n) ? counts[i] : 0;
    tmp[t] = v;
    __syncthreads();
    for (int off = 1; off < 256; off <<= 1) {
        const int a = (t >= off) ? tmp[t - off] : 0;
        __syncthreads();
        tmp[t] += a;
        __syncthreads();
    }
    if (i < n) starts[i] = tmp[t] - v;     // exclusive within block
    if (t == 255) blocksums[blockIdx.x] = tmp[255];
}

// ---------------- Kernel 2b: scan of block sums (single block) ----------------
__global__ __launch_bounds__(512) void scan2_kernel(
    int* __restrict__ blocksums,
    int* __restrict__ starts,
    int nblocks, int n)
{
    __shared__ int tmp[512];
    const int t = threadIdx.x;
    const int v = (t < nblocks) ? blocksums[t] : 0;
    tmp[t] = v;
    __syncthreads();
    for (int off = 1; off < 512; off <<= 1) {
        const int a = (t >= off) ? tmp[t - off] : 0;
        __syncthreads();
        tmp[t] += a;
        __syncthreads();
    }
    if (t < nblocks) blocksums[t] = tmp[t] - v;   // exclusive
    if (t == 511) starts[n] = tmp[511];           // total edge count kept
}

// ---------------- Kernel 2c: add block offsets ----------------
__global__ __launch_bounds__(256) void scan3_kernel(
    int* __restrict__ starts,
    const int* __restrict__ blocksums,
    int n)
{
    const int i = blockIdx.x * 256 + threadIdx.x;
    if (i < n) starts[i] += blocksums[i >> 8];
}

// ---------------- Kernel 3: reorder cols into CSR order ----------------
__global__ __launch_bounds__(256) void reorder_kernel(
    const int* __restrict__ row,
    const int* __restrict__ col,
    const int* __restrict__ starts,
    const int* __restrict__ rank,
    int* __restrict__ col_sorted,
    int nEdges)
{
    const int stride = gridDim.x * blockDim.x;
    for (int e = blockIdx.x * blockDim.x + threadIdx.x; e < nEdges; e += stride) {
        const int r = row[e];
        const int c = col[e];
        if (r != c) {
            col_sorted[starts[r] + rank[e]] = c;
        }
    }
}

// ---------------- Kernel 4: fused gather + MLP + BN-stats ----------------
// One wave per node row (grid-strided); lane = feature.
__global__ __launch_bounds__(256) void gather_mlp_stats_kernel(
    const float* __restrict__ x,
    const int* __restrict__ starts,
    const int* __restrict__ col_sorted,
    const float* __restrict__ W1,
    const float* __restrict__ b1,
    const float* __restrict__ W2,
    const float* __restrict__ b2,
    float* __restrict__ h_out,      // d_out, pre-BN h2
    float* __restrict__ stats,      // [0..63]=sum, [64..127]=sumsq
    int nNodes)
{
    __shared__ float sW1[F * F];
    __shared__ float sW2[F * F];
    __shared__ float sb1[F];
    __shared__ float sb2[F];

    for (int i = threadIdx.x; i < F * F; i += blockDim.x) {
        sW1[i] = W1[i];
        sW2[i] = W2[i];
    }
    if (threadIdx.x < F) {
        sb1[threadIdx.x] = b1[threadIdx.x];
        sb2[threadIdx.x] = b2[threadIdx.x];
    }
    __syncthreads();

    const int lane = threadIdx.x & 63;
    const int waveInBlock = threadIdx.x >> 6;
    const int waveId = blockIdx.x * (blockDim.x >> 6) + waveInBlock;
    const int nWaves = gridDim.x * (blockDim.x >> 6);

    float ssum = 0.0f;
    float ssq  = 0.0f;

    for (int r = waveId; r < nNodes; r += nWaves) {
        // gather-aggregate: v = x[r] + sum_{c in adj(r)} x[c]
        float v = x[r * F + lane];
        const int s  = starts[r];
        const int en = starts[r + 1];
        for (int j = s; j < en; j += 64) {
            const int nb = en - j < 64 ? en - j : 64;
            const int idx = (lane < nb) ? col_sorted[j + lane] : 0;
            for (int k = 0; k < nb; ++k) {
                const int c = __shfl(idx, k, 64);
                v += x[c * F + lane];
            }
        }

        // layer 1
        float acc = sb1[lane];
        #pragma unroll
        for (int k = 0; k < F; ++k) {
            const float xv = __shfl(v, k, 64);
            acc = fmaf(xv, sW1[k * F + lane], acc);
        }
        acc = fmaxf(acc, 0.0f);

        // layer 2
        float acc2 = sb2[lane];
        #pragma unroll
        for (int k = 0; k < F; ++k) {
            const float hv = __shfl(acc, k, 64);
            acc2 = fmaf(hv, sW2[k * F + lane], acc2);
        }
        acc2 = fmaxf(acc2, 0.0f);

        h_out[r * F + lane] = acc2;
        ssum += acc2;
        ssq = fmaf(acc2, acc2, ssq);
    }

    // block reduction -> one atomic per feature per block
    __shared__ float red[2][4][F];
    red[0][waveInBlock][lane] = ssum;
    red[1][waveInBlock][lane] = ssq;
    __syncthreads();
    if (threadIdx.x < F) {
        const int f = threadIdx.x;
        const float s = red[0][0][f] + red[0][1][f] + red[0][2][f] + red[0][3][f];
        const float q = red[1][0][f] + red[1][1][f] + red[1][2][f] + red[1][3][f];
        atomicAdd(&stats[f], s);
        atomicAdd(&stats[F + f], q);
    }
}

// ---------------- Kernel 5: BN finalize + normalize in place (float4) ----------------
__global__ __launch_bounds__(256) void bn_normalize_kernel(
    float4* __restrict__ h,         // d_out, in place
    const float* __restrict__ stats,
    const float* __restrict__ gamma,
    const float* __restrict__ beta,
    int nNodes)
{
    __shared__ float sscale[F];
    __shared__ float sshift[F];
    if (threadIdx.x < F) {
        const int f = threadIdx.x;
        const float invN = 1.0f / (float)nNodes;
        const float mean = stats[f] * invN;
        const float var  = stats[F + f] * invN - mean * mean;
        const float inv  = rsqrtf(var + BN_EPS);
        const float g    = gamma[f];
        sscale[f] = inv * g;
        sshift[f] = beta[f] - mean * inv * g;
    }
    __syncthreads();

    const int total4 = nNodes * (F / 4);
    const int stride = gridDim.x * blockDim.x;
    for (int i = blockIdx.x * blockDim.x + threadIdx.x; i < total4; i += stride) {
        const int f0 = (i & 15) * 4;
        float4 v = h[i];
        v.x = fmaf(v.x, sscale[f0 + 0], sshift[f0 + 0]);
        v.y = fmaf(v.y, sscale[f0 + 1], sshift[f0 + 1]);
        v.z = fmaf(v.z, sscale[f0 + 2], sshift[f0 + 2]);
        v.w = fmaf(v.w, sscale[f0 + 3], sshift[f0 + 3]);
        h[i] = v;
    }
}

extern "C" void kernel_launch(void* const* d_in, const int* in_sizes, int n_in,
                              void* d_out, int out_size, void* d_ws, size_t ws_size,
                              hipStream_t stream)
{
    const float* x     = (const float*)d_in[0];
    const int*   eidx  = (const int*)d_in[1];   // [2, E]: row then col
    const float* W1    = (const float*)d_in[2];
    const float* b1    = (const float*)d_in[3];
    const float* W2    = (const float*)d_in[4];
    const float* b2    = (const float*)d_in[5];
    const float* gamma = (const float*)d_in[6];
    const float* beta  = (const float*)d_in[7];

    const int nNodes = in_sizes[0] / F;
    const int nEdges = in_sizes[1] / 2;
    const int* row = eidx;
    const int* col = eidx + nEdges;

    // workspace layout (all 4-byte elems)
    char* wsp = (char*)d_ws;
    int*   counts     = (int*)wsp;                    wsp += (size_t)nNodes * 4;
    float* stats      = (float*)wsp;                  wsp += 128 * 4;
    int*   starts     = (int*)wsp;                    wsp += (size_t)(nNodes + 1) * 4;
    int*   blocksums  = (int*)wsp;                    wsp += 512 * 4;
    int*   rank       = (int*)wsp;                    wsp += (size_t)nEdges * 4;
    int*   col_sorted = (int*)wsp;                    wsp += (size_t)nEdges * 4;
    float* hbuf = (float*)d_out;

    const int nblocks_scan = (nNodes + 255) / 256;

    // zero counts + stats (adjacent) — must re-zero every call
    hipMemsetAsync(counts, 0, (size_t)nNodes * 4 + 128 * 4, stream);

    hist_kernel<<<2048, 256, 0, stream>>>(row, col, counts, rank, nEdges);
    scan1_kernel<<<nblocks_scan, 256, 0, stream>>>(counts, starts, blocksums, nNodes);
    scan2_kernel<<<1, 512, 0, stream>>>(blocksums, starts, nblocks_scan, nNodes);
    scan3_kernel<<<nblocks_scan, 256, 0, stream>>>(starts, blocksums, nNodes);
    reorder_kernel<<<2048, 256, 0, stream>>>(row, col, starts, rank, col_sorted, nEdges);

    gather_mlp_stats_kernel<<<2048, 256, 0, stream>>>(x, starts, col_sorted,
                                                      W1, b1, W2, b2,
                                                      hbuf, stats, nNodes);

    bn_normalize_kernel<<<2048, 256, 0, stream>>>((float4*)hbuf, stats, gamma, beta, nNodes);
}

// Round 3
// 332.849 us; speedup vs baseline: 1.5305x; 1.4747x over previous
//
#include <hip/hip_runtime.h>

#define F 64
#define BN_EPS 1e-5f

// ---------------- Kernel 1: degree histogram + per-edge rank ----------------
__global__ __launch_bounds__(256) void hist_kernel(
    const int* __restrict__ row,
    const int* __restrict__ col,
    int* __restrict__ counts,   // [N], pre-zeroed
    int* __restrict__ rank,     // [E]
    int nEdges)
{
    const int stride = gridDim.x * blockDim.x;
    for (int e = blockIdx.x * blockDim.x + threadIdx.x; e < nEdges; e += stride) {
        const int r = row[e];
        const int c = col[e];
        if (r != c) {
            rank[e] = atomicAdd(&counts[r], 1);
        }
    }
}

// ---------------- Kernel 2a: per-block inclusive scan of counts ----------------
__global__ __launch_bounds__(256) void scan1_kernel(
    const int* __restrict__ counts,
    int* __restrict__ starts,       // [N+1]
    int* __restrict__ blocksums,    // [nblocks]
    int n)
{
    __shared__ int tmp[256];
    const int t = threadIdx.x;
    const int i = blockIdx.x * 256 + t;
    const int v = (i < n) ? counts[i] : 0;
    tmp[t] = v;
    __syncthreads();
    for (int off = 1; off < 256; off <<= 1) {
        const int a = (t >= off) ? tmp[t - off] : 0;
        __syncthreads();
        tmp[t] += a;
        __syncthreads();
    }
    if (i < n) starts[i] = tmp[t] - v;     // exclusive within block
    if (t == 255) blocksums[blockIdx.x] = tmp[255];
}

// ---------------- Kernel 2b: scan of block sums (single block) ----------------
__global__ __launch_bounds__(512) void scan2_kernel(
    int* __restrict__ blocksums,
    int* __restrict__ starts,
    int nblocks, int n)
{
    __shared__ int tmp[512];
    const int t = threadIdx.x;
    const int v = (t < nblocks) ? blocksums[t] : 0;
    tmp[t] = v;
    __syncthreads();
    for (int off = 1; off < 512; off <<= 1) {
        const int a = (t >= off) ? tmp[t - off] : 0;
        __syncthreads();
        tmp[t] += a;
        __syncthreads();
    }
    if (t < nblocks) blocksums[t] = tmp[t] - v;   // exclusive
    if (t == 511) starts[n] = tmp[511];           // total kept-edge count
}

// ---------------- Kernel 2c: add block offsets ----------------
__global__ __launch_bounds__(256) void scan3_kernel(
    int* __restrict__ starts,
    const int* __restrict__ blocksums,
    int n)
{
    const int i = blockIdx.x * 256 + threadIdx.x;
    if (i < n) starts[i] += blocksums[i >> 8];
}

// ---------------- Kernel 3: reorder cols into CSR order ----------------
__global__ __launch_bounds__(256) void reorder_kernel(
    const int* __restrict__ row,
    const int* __restrict__ col,
    const int* __restrict__ starts,
    const int* __restrict__ rank,
    int* __restrict__ col_sorted,
    int nEdges)
{
    const int stride = gridDim.x * blockDim.x;
    for (int e = blockIdx.x * blockDim.x + threadIdx.x; e < nEdges; e += stride) {
        const int r = row[e];
        const int c = col[e];
        if (r != c) {
            col_sorted[starts[r] + rank[e]] = c;
        }
    }
}

// ---------------- Kernel 4: fused gather + MLP + BN-stats ----------------
// One wave per node row (grid-strided); lane = feature.
// Edge indices are read via wave-uniform (scalarizable) addresses; row loads
// are unrolled 8x for memory-level parallelism.
__global__ __launch_bounds__(256) void gather_mlp_stats_kernel(
    const float* __restrict__ x,
    const int* __restrict__ starts,
    const int* __restrict__ col_sorted,
    const float* __restrict__ W1,
    const float* __restrict__ b1,
    const float* __restrict__ W2,
    const float* __restrict__ b2,
    float* __restrict__ h_out,      // d_out, pre-BN h2
    float* __restrict__ stats,      // [0..63]=sum, [64..127]=sumsq
    int nNodes)
{
    __shared__ float sW1[F * F];
    __shared__ float sW2[F * F];
    __shared__ float sb1[F];
    __shared__ float sb2[F];

    for (int i = threadIdx.x; i < F * F; i += blockDim.x) {
        sW1[i] = W1[i];
        sW2[i] = W2[i];
    }
    if (threadIdx.x < F) {
        sb1[threadIdx.x] = b1[threadIdx.x];
        sb2[threadIdx.x] = b2[threadIdx.x];
    }
    __syncthreads();

    const int lane = threadIdx.x & 63;
    const int waveInBlock = threadIdx.x >> 6;
    const int waveId = blockIdx.x * (blockDim.x >> 6) + waveInBlock;
    const int nWaves = gridDim.x * (blockDim.x >> 6);

    float ssum = 0.0f;
    float ssq  = 0.0f;

    for (int r = waveId; r < nNodes; r += nWaves) {
        // wave-uniform edge range -> SGPRs, enables scalar index loads
        const int s  = __builtin_amdgcn_readfirstlane(starts[r]);
        const int en = __builtin_amdgcn_readfirstlane(starts[r + 1]);

        float v = x[(size_t)r * F + lane];

        int j = s;
        for (; j + 8 <= en; j += 8) {
            // uniform-address index loads (scalarizable)
            const int c0 = col_sorted[j + 0];
            const int c1 = col_sorted[j + 1];
            const int c2 = col_sorted[j + 2];
            const int c3 = col_sorted[j + 3];
            const int c4 = col_sorted[j + 4];
            const int c5 = col_sorted[j + 5];
            const int c6 = col_sorted[j + 6];
            const int c7 = col_sorted[j + 7];
            // 8 independent row loads in flight
            const float f0 = x[(size_t)c0 * F + lane];
            const float f1 = x[(size_t)c1 * F + lane];
            const float f2 = x[(size_t)c2 * F + lane];
            const float f3 = x[(size_t)c3 * F + lane];
            const float f4 = x[(size_t)c4 * F + lane];
            const float f5 = x[(size_t)c5 * F + lane];
            const float f6 = x[(size_t)c6 * F + lane];
            const float f7 = x[(size_t)c7 * F + lane];
            v += ((f0 + f1) + (f2 + f3)) + ((f4 + f5) + (f6 + f7));
        }
        for (; j < en; ++j) {
            const int c = col_sorted[j];
            v += x[(size_t)c * F + lane];
        }

        // layer 1
        float acc = sb1[lane];
        #pragma unroll
        for (int k = 0; k < F; ++k) {
            const float xv = __shfl(v, k, 64);
            acc = fmaf(xv, sW1[k * F + lane], acc);
        }
        acc = fmaxf(acc, 0.0f);

        // layer 2
        float acc2 = sb2[lane];
        #pragma unroll
        for (int k = 0; k < F; ++k) {
            const float hv = __shfl(acc, k, 64);
            acc2 = fmaf(hv, sW2[k * F + lane], acc2);
        }
        acc2 = fmaxf(acc2, 0.0f);

        h_out[(size_t)r * F + lane] = acc2;
        ssum += acc2;
        ssq = fmaf(acc2, acc2, ssq);
    }

    // block reduction -> one atomic per feature per block
    __shared__ float red[2][4][F];
    red[0][waveInBlock][lane] = ssum;
    red[1][waveInBlock][lane] = ssq;
    __syncthreads();
    if (threadIdx.x < F) {
        const int f = threadIdx.x;
        const float s = red[0][0][f] + red[0][1][f] + red[0][2][f] + red[0][3][f];
        const float q = red[1][0][f] + red[1][1][f] + red[1][2][f] + red[1][3][f];
        atomicAdd(&stats[f], s);
        atomicAdd(&stats[F + f], q);
    }
}

// ---------------- Kernel 5: BN finalize + normalize in place (float4) ----------------
__global__ __launch_bounds__(256) void bn_normalize_kernel(
    float4* __restrict__ h,         // d_out, in place
    const float* __restrict__ stats,
    const float* __restrict__ gamma,
    const float* __restrict__ beta,
    int nNodes)
{
    __shared__ float sscale[F];
    __shared__ float sshift[F];
    if (threadIdx.x < F) {
        const int f = threadIdx.x;
        const float invN = 1.0f / (float)nNodes;
        const float mean = stats[f] * invN;
        const float var  = stats[F + f] * invN - mean * mean;
        const float inv  = rsqrtf(var + BN_EPS);
        const float g    = gamma[f];
        sscale[f] = inv * g;
        sshift[f] = beta[f] - mean * inv * g;
    }
    __syncthreads();

    const int total4 = nNodes * (F / 4);
    const int stride = gridDim.x * blockDim.x;
    for (int i = blockIdx.x * blockDim.x + threadIdx.x; i < total4; i += stride) {
        const int f0 = (i & 15) * 4;
        float4 v = h[i];
        v.x = fmaf(v.x, sscale[f0 + 0], sshift[f0 + 0]);
        v.y = fmaf(v.y, sscale[f0 + 1], sshift[f0 + 1]);
        v.z = fmaf(v.z, sscale[f0 + 2], sshift[f0 + 2]);
        v.w = fmaf(v.w, sscale[f0 + 3], sshift[f0 + 3]);
        h[i] = v;
    }
}

extern "C" void kernel_launch(void* const* d_in, const int* in_sizes, int n_in,
                              void* d_out, int out_size, void* d_ws, size_t ws_size,
                              hipStream_t stream)
{
    const float* x     = (const float*)d_in[0];
    const int*   eidx  = (const int*)d_in[1];   // [2, E]: row then col
    const float* W1    = (const float*)d_in[2];
    const float* b1    = (const float*)d_in[3];
    const float* W2    = (const float*)d_in[4];
    const float* b2    = (const float*)d_in[5];
    const float* gamma = (const float*)d_in[6];
    const float* beta  = (const float*)d_in[7];

    const int nNodes = in_sizes[0] / F;
    const int nEdges = in_sizes[1] / 2;
    const int* row = eidx;
    const int* col = eidx + nEdges;

    // workspace layout (all 4-byte elems)
    char* wsp = (char*)d_ws;
    int*   counts     = (int*)wsp;                    wsp += (size_t)nNodes * 4;
    float* stats      = (float*)wsp;                  wsp += 128 * 4;
    int*   starts     = (int*)wsp;                    wsp += (size_t)(nNodes + 1) * 4;
    int*   blocksums  = (int*)wsp;                    wsp += 512 * 4;
    int*   rank       = (int*)wsp;                    wsp += (size_t)nEdges * 4;
    int*   col_sorted = (int*)wsp;                    wsp += (size_t)nEdges * 4;
    float* hbuf = (float*)d_out;

    const int nblocks_scan = (nNodes + 255) / 256;

    // zero counts + stats (adjacent) — must re-zero every call
    hipMemsetAsync(counts, 0, (size_t)nNodes * 4 + 128 * 4, stream);

    hist_kernel<<<2048, 256, 0, stream>>>(row, col, counts, rank, nEdges);
    scan1_kernel<<<nblocks_scan, 256, 0, stream>>>(counts, starts, blocksums, nNodes);
    scan2_kernel<<<1, 512, 0, stream>>>(blocksums, starts, nblocks_scan, nNodes);
    scan3_kernel<<<nblocks_scan, 256, 0, stream>>>(starts, blocksums, nNodes);
    reorder_kernel<<<2048, 256, 0, stream>>>(row, col, starts, rank, col_sorted, nEdges);

    gather_mlp_stats_kernel<<<2048, 256, 0, stream>>>(x, starts, col_sorted,
                                                      W1, b1, W2, b2,
                                                      hbuf, stats, nNodes);

    bn_normalize_kernel<<<2048, 256, 0, stream>>>((float4*)hbuf, stats, gamma, beta, nNodes);
}